// Round 19
// baseline (454.912 us; speedup 1.0000x reference)
//
#include <hip/hip_runtime.h>
#include <hip/hip_bf16.h>

// InstanSeg v18: best-of assembly. R8-R17 conclusion: every restructure of
// the v6b pix (16px/wave, full-W2-in-regs, 2304 blocks) lost to it; h-split
// duplicates ~50% of VALU work. This is v6b pix + only the proven grafts:
// ballot-prefix list (deterministic), 2-stage D prefetch, center-out rows.
// merge v2 (f16 dl + mpk staging) kept from v11.

#define HH    384
#define WW    384
#define NE    32
#define NK    256
#define HALF  64
#define HWSZ  (HH * WW)
#define EPSV  1e-6f
#define CAPX  192     // pix/merge per-block (64px span) candidate cap

typedef _Float16 half8 __attribute__((ext_vector_type(8)));
typedef _Float16 half2v __attribute__((ext_vector_type(2)));
typedef float floatx4 __attribute__((ext_vector_type(4)));

#define MFMA16(a, b, c) __builtin_amdgcn_mfma_f32_16x16x32_f16((a), (b), (c), 0, 0, 0)

__device__ __forceinline__ half2v pk_f16(float a, float b) {
    return __builtin_bit_cast(half2v, __builtin_amdgcn_cvt_pkrtz(a, b));
}

__device__ __forceinline__ int row_order(int ri) {
    return (ri & 1) ? (191 - (ri >> 1)) : (192 + (ri >> 1));
}

// ---- ws layout (float-element offsets) ----
#define WS_DIST   0            // 4,194,304 f32 (16 MB)
#define WS_MSYM   4194304      // 65,536 f32
#define WS_W2F    4259840      // 16,384 f16 = 8,192 f32
#define WS_D      4268032      // 32,768 f16 = 16,384 f32
#define WS_CENTER 4284416      // 256 f32
#define WS_G      5026560      // 18,874,368 f16 = 9,437,184 f32

// ---------------------------------------------------------------- prep ----
__global__ void prep_kernel(const float* __restrict__ M, const float* __restrict__ W1,
                            const float* __restrict__ W2, const float* __restrict__ c,
                            const float* __restrict__ b1,
                            float* __restrict__ Msym, _Float16* __restrict__ W2f,
                            _Float16* __restrict__ D) {
    int idx = blockIdx.x * 256 + threadIdx.x;
    {   // Msym
        int i = idx >> 8, j = idx & 255;
        Msym[idx] = (i == j) ? 1.0f : 0.5f * (M[i * NK + j] + M[j * NK + i]);
    }
    if (idx < 2048) {   // W2f B-frags: lane l elem j = W2[32s+8(l>>4)+j][16nt+(l&15)]
        int l = idx & 63;
        int col = ((idx >> 8) << 4) + (l & 15);
        int kb = ((idx >> 6) & 3) * 32 + 8 * (l >> 4);
        #pragma unroll
        for (int j = 0; j < 8; ++j)
            W2f[idx * 8 + j] = (_Float16)W2[(kb + j) * 128 + col];
    }
    if (idx < 32768) {  // D[k][h] = W1^T c_k - b1
        int k = idx >> 7, h = idx & 127;
        float s = -b1[h];
        #pragma unroll 8
        for (int e = 0; e < NE; ++e) s = fmaf(c[k * NE + e], W1[e * 128 + h], s);
        D[idx] = (_Float16)s;
    }
}

// --------------------------------------------------------------- gfeat ----
__global__ __launch_bounds__(256)
void gfeat_kernel(const float* __restrict__ x, const float* __restrict__ sigma,
                  const float* __restrict__ W1, _Float16* __restrict__ G) {
    int px = blockIdx.x * 256 + threadIdx.x;
    float f[34];
    #pragma unroll
    for (int e = 0; e < NE; ++e) f[e] = x[e * HWSZ + px];
    f[32] = sigma[px];
    f[33] = sigma[HWSZ + px];
    _Float16* gp = G + (size_t)px * 128;
    #pragma unroll 1
    for (int h0 = 0; h0 < 128; h0 += 8) {
        half8 hv;
        #pragma unroll
        for (int j = 0; j < 8; ++j) {
            float z = 0.0f;
            const float* w1 = W1 + (h0 + j);
            #pragma unroll
            for (int e = 0; e < 34; ++e) z = fmaf(f[e], w1[e * 128], z);
            hv[j] = (_Float16)z;
        }
        *(half8*)(gp + h0) = hv;
    }
}

// -------------------------------------------------------------- center2 ---
__global__ __launch_bounds__(128)
void center2_kernel(const _Float16* __restrict__ G, const _Float16* __restrict__ D,
                    const float* __restrict__ W2, const float* __restrict__ b2,
                    const float* __restrict__ W3, const float* __restrict__ b3,
                    const int* __restrict__ cent, float* __restrict__ center) {
    __shared__ float h1s[128];
    __shared__ float red[2];
    int k = blockIdx.x, j = threadIdx.x;
    int cy0 = cent[2 * k], cx0 = cent[2 * k + 1];
    const _Float16* g = G + ((size_t)cy0 * WW + cx0) * 128;
    h1s[j] = fmaxf((float)g[j] - (float)D[k * 128 + j], 0.0f);
    __syncthreads();
    float acc = 0.0f;
    #pragma unroll 8
    for (int i = 0; i < 128; ++i) acc = fmaf(h1s[i], W2[i * 128 + j], acc);
    float p = fmaxf(acc + b2[j], 0.0f) * W3[j];
    #pragma unroll
    for (int m = 1; m < 64; m <<= 1) p += __shfl_xor(p, m, 64);
    if ((j & 63) == 0) red[j >> 6] = p;
    __syncthreads();
    if (j == 0) center[k] = red[0] + red[1] + b3[0];
}

// ----------------------------------------------------------------- pix ----
// 2304 blocks (384 rows x 6 xtiles of 64 px) x 256 thr; wave = 16 px.
// v6b compute path + ballot list + 2-stage D prefetch + center-out rows.
__global__ __launch_bounds__(256)
void pix_kernel(const _Float16* __restrict__ G, const _Float16* __restrict__ D,
                const _Float16* __restrict__ W2f, const int* __restrict__ cent,
                const float* __restrict__ b2, const float* __restrict__ W3,
                const float* __restrict__ b3, const float* __restrict__ center,
                float* __restrict__ dist) {
    __shared__ int   sjw[CAPX];
    __shared__ float wc[CAPX];
    __shared__ int   scnt;

    const int tid = threadIdx.x;
    const int l   = tid & 63;
    const int wv  = tid >> 6;
    const int lg  = l >> 4;
    const int xi  = l & 15;

    const int r   = row_order(blockIdx.x / 6);
    const int xt  = blockIdx.x % 6;
    const int wx0 = xt * 64 + wv * 16;           // wave's 16-px x-origin

    // ---- wave 0: deterministic ballot-prefix list for the 64-px span ----
    if (wv == 0) {
        int base = 0;
        const int2* c2 = (const int2*)cent;
        #pragma unroll
        for (int cch = 0; cch < 4; ++cch) {
            int j = cch * 64 + l;
            int2 cc = c2[j];
            int ty = min(max(cc.x, HALF), HH - HALF) - HALF;
            int tx = min(max(cc.y, HALF), WW - HALF) - HALF;
            bool f = (r >= ty) && (r < ty + 128) &&
                     (tx <= xt * 64 + 63) && (tx + 127 >= xt * 64);
            unsigned long long m = __ballot(f);
            int pos = base + __popcll(m & ((1ull << l) - 1ull));
            if (f && pos < CAPX) {
                sjw[pos] = (j << 20) | (ty << 10) | tx;
                wc[pos]  = center[j];
            }
            base += __popcll(m);
        }
        if (l == 0) scnt = min(base, CAPX);
    }

    // ---- loop-invariant registers (v6b layout: full W2 per wave) ----
    half8 B2w[8][4];
    const half8* W2f8 = (const half8*)W2f;
    #pragma unroll
    for (int n = 0; n < 8; ++n)
        #pragma unroll
        for (int s = 0; s < 4; ++s) B2w[n][s] = W2f8[(n * 4 + s) * 64 + l];

    float b2v[8][4];
    half2v w3pk[8][2];
    #pragma unroll
    for (int n = 0; n < 8; ++n) {
        #pragma unroll
        for (int q = 0; q < 4; ++q) b2v[n][q] = b2[16 * n + 4 * lg + q];
        #pragma unroll
        for (int q = 0; q < 2; ++q)
            w3pk[n][q] = half2v{(_Float16)W3[16 * n + 4 * lg + 2 * q],
                                (_Float16)W3[16 * n + 4 * lg + 2 * q + 1]};
    }
    const float b3s = b3[0];

    // G fragments for this wave's 16 px (loaded ONCE)
    half8 gA[4];
    {
        const char* Gb = (const char*)G + ((size_t)r * WW + wx0 + xi) * 256 + lg * 16;
        #pragma unroll
        for (int s = 0; s < 4; ++s) gA[s] = *(const half8*)(Gb + s * 64);
    }
    const half8 hz = half8{};
    const char* Dc = (const char*)D;

    __syncthreads();
    const int nc = scnt;

    auto loadD = [&](half8* dst, int cp) {
        const char* Dp = Dc + (cp >> 20) * 256 + lg * 16;
        #pragma unroll
        for (int s = 0; s < 4; ++s) dst[s] = *(const half8*)(Dp + s * 64);
    };

    auto overlaps = [&](int cp) -> bool {
        int tx = cp & 1023;
        return tx <= wx0 + 15 && tx + 127 >= wx0;
    };

    auto compute = [&](const half8* Dv, int cp, float bc) {
        half8 hin[4];
        #pragma unroll
        for (int s = 0; s < 4; ++s)
            hin[s] = __builtin_elementwise_max(gA[s] - Dv[s], hz);

        float p = 0.0f;
        #pragma unroll
        for (int n = 0; n < 8; ++n) {
            floatx4 acc = floatx4{b2v[n][0], b2v[n][1], b2v[n][2], b2v[n][3]};
            #pragma unroll
            for (int s = 0; s < 4; ++s)
                acc = MFMA16(B2w[n][s], hin[s], acc);    // D[row=h2, col=px]
            half2v h0 = __builtin_elementwise_max(pk_f16(acc[0], acc[1]), half2v{});
            half2v h1 = __builtin_elementwise_max(pk_f16(acc[2], acc[3]), half2v{});
            p = __builtin_amdgcn_fdot2(h0, w3pk[n][0], p, false);
            p = __builtin_amdgcn_fdot2(h1, w3pk[n][1], p, false);
        }
        p += __shfl_xor(p, 16, 64);
        p += __shfl_xor(p, 32, 64);

        if (lg == 0) {
            int tx = cp & 1023, ty = (cp >> 10) & 1023, j = cp >> 20;
            int px = wx0 + xi;
            unsigned dx = (unsigned)(px - tx);
            if (dx < 128u) {
                float d = p + b3s;
                float mm = fmaxf(fmaxf(d, bc), 0.0f);
                float lgv = mm + __logf(__expf(0.0f - mm) + __expf(d - mm) +
                                        __expf(bc - mm));
                dist[((size_t)j << 14) + ((r - ty) << 7) + (int)dx] = d + bc - lgv;
            }
        }
    };

    // ---- 2-stage software-pipelined candidate loop (skip is wave-uniform) ----
    half8 Da[4], Db[4];
    int cpA = 0, cpB = 0;
    float bcA = 0.0f, bcB = 0.0f;
    if (nc > 0) { cpA = sjw[0]; bcA = wc[0]; loadD(Da, cpA); }
    #pragma unroll 1
    for (int i = 0; i < nc; i += 2) {
        if (i + 1 < nc) { cpB = sjw[i + 1]; bcB = wc[i + 1]; loadD(Db, cpB); }
        if (overlaps(cpA)) compute(Da, cpA, bcA);
        if (i + 1 >= nc) break;
        if (i + 2 < nc) { cpA = sjw[i + 2]; bcA = wc[i + 2]; loadD(Da, cpA); }
        if (overlaps(cpB)) compute(Db, cpB, bcB);
    }
}

// --------------------------------------------------------------- merge ----
// 2304 blocks of 256. dl staged as f16 (24KB) + per-t (m,tx) pairs in LDS.
__global__ __launch_bounds__(256)
void merge_kernel(const float* __restrict__ dist, const int* __restrict__ cent,
                  const float* __restrict__ Msym, float* __restrict__ out) {
    __shared__ _Float16 dl[CAPX][64];    // 24 KB
    __shared__ int   sjw[CAPX];
    __shared__ int2  mpk[4][CAPX];       // 6 KB {m bits, tx}
    __shared__ int   scnt;

    const int tid = threadIdx.x;
    const int l   = tid & 63;
    const int wv  = tid >> 6;
    const int r   = row_order(blockIdx.x / 6);
    const int xt  = blockIdx.x % 6;
    const int px  = xt * 64 + l;

    if (wv == 0) {
        int base = 0;
        const int2* c2 = (const int2*)cent;
        #pragma unroll
        for (int cch = 0; cch < 4; ++cch) {
            int j = cch * 64 + l;
            int2 cc = c2[j];
            int ty = min(max(cc.x, HALF), HH - HALF) - HALF;
            int tx = min(max(cc.y, HALF), WW - HALF) - HALF;
            bool f = (r >= ty) && (r < ty + 128) &&
                     (tx <= xt * 64 + 63) && (tx + 127 >= xt * 64);
            unsigned long long m = __ballot(f);
            int pos = base + __popcll(m & ((1ull << l) - 1ull));
            if (f && pos < CAPX) sjw[pos] = (j << 20) | (ty << 10) | tx;
            base += __popcll(m);
        }
        if (l == 0) scnt = min(base, CAPX);
    }
    __syncthreads();
    const int nc = scnt;

    #pragma unroll 1
    for (int j = wv; j < nc; j += 4) {
        int cp = sjw[j];
        int tx = cp & 1023, ty = (cp >> 10) & 1023, jj = cp >> 20;
        unsigned dx = (unsigned)(px - tx);
        float v = 0.0f;
        if (dx < 128u) v = dist[((size_t)jj << 14) + ((r - ty) << 7) + (int)dx];
        dl[j][l] = (_Float16)v;
    }
    __syncthreads();

    #pragma unroll 1
    for (int t = wv; t < nc; t += 4) {
        int cpt = sjw[t];
        int kt = cpt >> 20;
        const float* mrow = Msym + kt * NK;
        #pragma unroll
        for (int cch = 0; cch < 3; ++cch) {
            int j2 = cch * 64 + l;
            if (j2 < nc) {
                int cj = sjw[j2];
                mpk[wv][j2] = int2{__builtin_bit_cast(int, mrow[cj >> 20]),
                                   cj & 1023};
            }
        }
        float num = 0.0f, den = 0.0f;
        #pragma unroll 4
        for (int j = 0; j < nc; ++j) {
            int2 mp = mpk[wv][j];
            float m = __builtin_bit_cast(float, mp.x);
            num = fmaf(m, (float)dl[j][l], num);
            unsigned dxj = (unsigned)(px - mp.y);
            den += (dxj < 128u) ? m : 0.0f;
        }
        unsigned dxk = (unsigned)(px - (cpt & 1023));
        if (dxk < 128u)
            out[((size_t)kt << 14) + ((r - ((cpt >> 10) & 1023)) << 7) + (int)dxk] =
                num / fmaxf(den, EPSV);
    }
}

// -------------------------------------------------------------- launch ----
extern "C" void kernel_launch(void* const* d_in, const int* in_sizes, int n_in,
                              void* d_out, int out_size, void* d_ws, size_t ws_size,
                              hipStream_t stream) {
    const float* x     = (const float*)d_in[0];
    const float* sigma = (const float*)d_in[1];
    const float* c     = (const float*)d_in[2];
    const int*   cent  = (const int*)d_in[3];
    const float* M     = (const float*)d_in[4];
    const float* W1    = (const float*)d_in[5];
    const float* b1    = (const float*)d_in[6];
    const float* W2    = (const float*)d_in[7];
    const float* b2    = (const float*)d_in[8];
    const float* W3    = (const float*)d_in[9];
    const float* b3    = (const float*)d_in[10];
    float* out = (float*)d_out;

    float* ws       = (float*)d_ws;
    float* dist     = ws + WS_DIST;
    float* Msym     = ws + WS_MSYM;
    _Float16* W2f   = (_Float16*)(ws + WS_W2F);
    _Float16* D     = (_Float16*)(ws + WS_D);
    float* center   = ws + WS_CENTER;
    _Float16* G     = (_Float16*)(ws + WS_G);

    prep_kernel<<<256, 256, 0, stream>>>(M, W1, W2, c, b1, Msym, W2f, D);
    gfeat_kernel<<<576, 256, 0, stream>>>(x, sigma, W1, G);
    center2_kernel<<<256, 128, 0, stream>>>(G, D, W2, b2, W3, b3, cent, center);
    pix_kernel<<<2304, 256, 0, stream>>>(G, D, W2f, cent, b2, W3, b3, center, dist);
    merge_kernel<<<2304, 256, 0, stream>>>(dist, cent, Msym, out);
}

// Round 20
// 331.761 us; speedup vs baseline: 1.3712x; 1.3712x over previous
//
#include <hip/hip_runtime.h>
#include <hip/hip_bf16.h>

// InstanSeg v19: pix reverted to the measured-best v6b structure (R7:
// 220us, 18.7% occ, VGPR 128). R19 lesson: the 2-stage D-prefetch's 32
// extra live VGPRs pushed total regs past the 256 bucket -> waves/CU
// halved (occ 18.7->9.5). v6b loads D inline; only zero-register grafts
// kept: ballot-prefix list (determinism), center-out row order.
// merge v2 (f16 dl + mpk staging, ~55us) kept.

#define HH    384
#define WW    384
#define NE    32
#define NK    256
#define HALF  64
#define HWSZ  (HH * WW)
#define EPSV  1e-6f
#define CAPX  192     // pix/merge per-block (64px span) candidate cap

typedef _Float16 half8 __attribute__((ext_vector_type(8)));
typedef _Float16 half2v __attribute__((ext_vector_type(2)));
typedef float floatx4 __attribute__((ext_vector_type(4)));

#define MFMA16(a, b, c) __builtin_amdgcn_mfma_f32_16x16x32_f16((a), (b), (c), 0, 0, 0)

__device__ __forceinline__ half2v pk_f16(float a, float b) {
    return __builtin_bit_cast(half2v, __builtin_amdgcn_cvt_pkrtz(a, b));
}

__device__ __forceinline__ int row_order(int ri) {
    return (ri & 1) ? (191 - (ri >> 1)) : (192 + (ri >> 1));
}

// ---- ws layout (float-element offsets) ----
#define WS_DIST   0            // 4,194,304 f32 (16 MB)
#define WS_MSYM   4194304      // 65,536 f32
#define WS_W2F    4259840      // 16,384 f16 = 8,192 f32
#define WS_D      4268032      // 32,768 f16 = 16,384 f32
#define WS_CENTER 4284416      // 256 f32
#define WS_G      5026560      // 18,874,368 f16 = 9,437,184 f32

// ---------------------------------------------------------------- prep ----
__global__ void prep_kernel(const float* __restrict__ M, const float* __restrict__ W1,
                            const float* __restrict__ W2, const float* __restrict__ c,
                            const float* __restrict__ b1,
                            float* __restrict__ Msym, _Float16* __restrict__ W2f,
                            _Float16* __restrict__ D) {
    int idx = blockIdx.x * 256 + threadIdx.x;
    {   // Msym
        int i = idx >> 8, j = idx & 255;
        Msym[idx] = (i == j) ? 1.0f : 0.5f * (M[i * NK + j] + M[j * NK + i]);
    }
    if (idx < 2048) {   // W2f B-frags: lane l elem j = W2[32s+8(l>>4)+j][16nt+(l&15)]
        int l = idx & 63;
        int col = ((idx >> 8) << 4) + (l & 15);
        int kb = ((idx >> 6) & 3) * 32 + 8 * (l >> 4);
        #pragma unroll
        for (int j = 0; j < 8; ++j)
            W2f[idx * 8 + j] = (_Float16)W2[(kb + j) * 128 + col];
    }
    if (idx < 32768) {  // D[k][h] = W1^T c_k - b1
        int k = idx >> 7, h = idx & 127;
        float s = -b1[h];
        #pragma unroll 8
        for (int e = 0; e < NE; ++e) s = fmaf(c[k * NE + e], W1[e * 128 + h], s);
        D[idx] = (_Float16)s;
    }
}

// --------------------------------------------------------------- gfeat ----
__global__ __launch_bounds__(256)
void gfeat_kernel(const float* __restrict__ x, const float* __restrict__ sigma,
                  const float* __restrict__ W1, _Float16* __restrict__ G) {
    int px = blockIdx.x * 256 + threadIdx.x;
    float f[34];
    #pragma unroll
    for (int e = 0; e < NE; ++e) f[e] = x[e * HWSZ + px];
    f[32] = sigma[px];
    f[33] = sigma[HWSZ + px];
    _Float16* gp = G + (size_t)px * 128;
    #pragma unroll 1
    for (int h0 = 0; h0 < 128; h0 += 8) {
        half8 hv;
        #pragma unroll
        for (int j = 0; j < 8; ++j) {
            float z = 0.0f;
            const float* w1 = W1 + (h0 + j);
            #pragma unroll
            for (int e = 0; e < 34; ++e) z = fmaf(f[e], w1[e * 128], z);
            hv[j] = (_Float16)z;
        }
        *(half8*)(gp + h0) = hv;
    }
}

// -------------------------------------------------------------- center2 ---
__global__ __launch_bounds__(128)
void center2_kernel(const _Float16* __restrict__ G, const _Float16* __restrict__ D,
                    const float* __restrict__ W2, const float* __restrict__ b2,
                    const float* __restrict__ W3, const float* __restrict__ b3,
                    const int* __restrict__ cent, float* __restrict__ center) {
    __shared__ float h1s[128];
    __shared__ float red[2];
    int k = blockIdx.x, j = threadIdx.x;
    int cy0 = cent[2 * k], cx0 = cent[2 * k + 1];
    const _Float16* g = G + ((size_t)cy0 * WW + cx0) * 128;
    h1s[j] = fmaxf((float)g[j] - (float)D[k * 128 + j], 0.0f);
    __syncthreads();
    float acc = 0.0f;
    #pragma unroll 8
    for (int i = 0; i < 128; ++i) acc = fmaf(h1s[i], W2[i * 128 + j], acc);
    float p = fmaxf(acc + b2[j], 0.0f) * W3[j];
    #pragma unroll
    for (int m = 1; m < 64; m <<= 1) p += __shfl_xor(p, m, 64);
    if ((j & 63) == 0) red[j >> 6] = p;
    __syncthreads();
    if (j == 0) center[k] = red[0] + red[1] + b3[0];
}

// ----------------------------------------------------------------- pix ----
// 2304 blocks (384 rows x 6 xtiles of 64 px) x 256 thr; wave = 16 px.
// v6b structure: D loaded inline in the loop body (no prefetch registers).
__global__ __launch_bounds__(256)
void pix_kernel(const _Float16* __restrict__ G, const _Float16* __restrict__ D,
                const _Float16* __restrict__ W2f, const int* __restrict__ cent,
                const float* __restrict__ b2, const float* __restrict__ W3,
                const float* __restrict__ b3, const float* __restrict__ center,
                float* __restrict__ dist) {
    __shared__ int   sjw[CAPX];
    __shared__ float sctr[CAPX];
    __shared__ int   scnt;

    const int tid = threadIdx.x;
    const int l   = tid & 63;
    const int wv  = tid >> 6;
    const int lg  = l >> 4;
    const int xi  = l & 15;

    const int r   = row_order(blockIdx.x / 6);
    const int xt  = blockIdx.x % 6;
    const int wx0 = xt * 64 + wv * 16;           // wave's 16-px x-origin

    // ---- wave 0: deterministic ballot-prefix list for the 64-px span ----
    if (wv == 0) {
        int base = 0;
        const int2* c2 = (const int2*)cent;
        #pragma unroll
        for (int cch = 0; cch < 4; ++cch) {
            int j = cch * 64 + l;
            int2 cc = c2[j];
            int ty = min(max(cc.x, HALF), HH - HALF) - HALF;
            int tx = min(max(cc.y, HALF), WW - HALF) - HALF;
            bool f = (r >= ty) && (r < ty + 128) &&
                     (tx <= xt * 64 + 63) && (tx + 127 >= xt * 64);
            unsigned long long m = __ballot(f);
            int pos = base + __popcll(m & ((1ull << l) - 1ull));
            if (f && pos < CAPX) {
                sjw[pos]  = (j << 20) | (ty << 10) | tx;
                sctr[pos] = center[j];
            }
            base += __popcll(m);
        }
        if (l == 0) scnt = min(base, CAPX);
    }

    // ---- loop-invariant registers (v6b layout: full W2 per wave) ----
    half8 B2w[8][4];
    const half8* W2f8 = (const half8*)W2f;
    #pragma unroll
    for (int n = 0; n < 8; ++n)
        #pragma unroll
        for (int s = 0; s < 4; ++s) B2w[n][s] = W2f8[(n * 4 + s) * 64 + l];

    float b2v[8][4];
    half2v w3pk[8][2];
    #pragma unroll
    for (int n = 0; n < 8; ++n) {
        #pragma unroll
        for (int q = 0; q < 4; ++q) b2v[n][q] = b2[16 * n + 4 * lg + q];
        #pragma unroll
        for (int q = 0; q < 2; ++q)
            w3pk[n][q] = half2v{(_Float16)W3[16 * n + 4 * lg + 2 * q],
                                (_Float16)W3[16 * n + 4 * lg + 2 * q + 1]};
    }
    const float b3s = b3[0];

    // G fragments for this wave's 16 px (loaded ONCE)
    half8 gA[4];
    {
        const char* Gb = (const char*)G + ((size_t)r * WW + wx0 + xi) * 256 + lg * 16;
        #pragma unroll
        for (int s = 0; s < 4; ++s) gA[s] = *(const half8*)(Gb + s * 64);
    }
    const half8 hz = half8{};
    __syncthreads();
    const int ncand = scnt;

    // ---- k-loop over covering windows (v6b: D loaded inline) ----
    #pragma unroll 1
    for (int i = 0; i < ncand; ++i) {
        int cp = sjw[i];
        int tx = cp & 1023, ty = (cp >> 10) & 1023, j = cp >> 20;
        if (tx > wx0 + 15 || tx + 127 < wx0) continue;      // wave x-filter

        const char* Dp = (const char*)D + j * 256 + lg * 16;
        half8 hin[4];
        #pragma unroll
        for (int s = 0; s < 4; ++s) {
            half8 dv = *(const half8*)(Dp + s * 64);
            hin[s] = __builtin_elementwise_max(gA[s] - dv, hz);
        }

        float p = 0.0f;
        #pragma unroll
        for (int n = 0; n < 8; ++n) {
            floatx4 acc = floatx4{b2v[n][0], b2v[n][1], b2v[n][2], b2v[n][3]};
            #pragma unroll
            for (int s = 0; s < 4; ++s)
                acc = MFMA16(B2w[n][s], hin[s], acc);       // D[row=h2, col=px]
            half2v h0 = __builtin_elementwise_max(pk_f16(acc[0], acc[1]), half2v{});
            half2v h1 = __builtin_elementwise_max(pk_f16(acc[2], acc[3]), half2v{});
            p = __builtin_amdgcn_fdot2(h0, w3pk[n][0], p, false);
            p = __builtin_amdgcn_fdot2(h1, w3pk[n][1], p, false);
        }
        p += __shfl_xor(p, 16, 64);
        p += __shfl_xor(p, 32, 64);

        if (lg == 0) {
            int xcol = wx0 + xi;
            unsigned dx = (unsigned)(xcol - tx);
            if (dx < 128u) {
                float d = p + b3s;
                float bc = sctr[i];
                float mm = fmaxf(fmaxf(d, bc), 0.0f);
                float lgv = mm + __logf(__expf(0.0f - mm) + __expf(d - mm) +
                                        __expf(bc - mm));
                dist[((size_t)j << 14) + ((r - ty) << 7) + (int)dx] = d + bc - lgv;
            }
        }
    }
}

// --------------------------------------------------------------- merge ----
// 2304 blocks of 256. dl staged as f16 (24KB) + per-t (m,tx) pairs in LDS.
__global__ __launch_bounds__(256)
void merge_kernel(const float* __restrict__ dist, const int* __restrict__ cent,
                  const float* __restrict__ Msym, float* __restrict__ out) {
    __shared__ _Float16 dl[CAPX][64];    // 24 KB
    __shared__ int   sjw[CAPX];
    __shared__ int2  mpk[4][CAPX];       // 6 KB {m bits, tx}
    __shared__ int   scnt;

    const int tid = threadIdx.x;
    const int l   = tid & 63;
    const int wv  = tid >> 6;
    const int r   = row_order(blockIdx.x / 6);
    const int xt  = blockIdx.x % 6;
    const int px  = xt * 64 + l;

    if (wv == 0) {
        int base = 0;
        const int2* c2 = (const int2*)cent;
        #pragma unroll
        for (int cch = 0; cch < 4; ++cch) {
            int j = cch * 64 + l;
            int2 cc = c2[j];
            int ty = min(max(cc.x, HALF), HH - HALF) - HALF;
            int tx = min(max(cc.y, HALF), WW - HALF) - HALF;
            bool f = (r >= ty) && (r < ty + 128) &&
                     (tx <= xt * 64 + 63) && (tx + 127 >= xt * 64);
            unsigned long long m = __ballot(f);
            int pos = base + __popcll(m & ((1ull << l) - 1ull));
            if (f && pos < CAPX) sjw[pos] = (j << 20) | (ty << 10) | tx;
            base += __popcll(m);
        }
        if (l == 0) scnt = min(base, CAPX);
    }
    __syncthreads();
    const int nc = scnt;

    #pragma unroll 1
    for (int j = wv; j < nc; j += 4) {
        int cp = sjw[j];
        int tx = cp & 1023, ty = (cp >> 10) & 1023, jj = cp >> 20;
        unsigned dx = (unsigned)(px - tx);
        float v = 0.0f;
        if (dx < 128u) v = dist[((size_t)jj << 14) + ((r - ty) << 7) + (int)dx];
        dl[j][l] = (_Float16)v;
    }
    __syncthreads();

    #pragma unroll 1
    for (int t = wv; t < nc; t += 4) {
        int cpt = sjw[t];
        int kt = cpt >> 20;
        const float* mrow = Msym + kt * NK;
        #pragma unroll
        for (int cch = 0; cch < 3; ++cch) {
            int j2 = cch * 64 + l;
            if (j2 < nc) {
                int cj = sjw[j2];
                mpk[wv][j2] = int2{__builtin_bit_cast(int, mrow[cj >> 20]),
                                   cj & 1023};
            }
        }
        float num = 0.0f, den = 0.0f;
        #pragma unroll 4
        for (int j = 0; j < nc; ++j) {
            int2 mp = mpk[wv][j];
            float m = __builtin_bit_cast(float, mp.x);
            num = fmaf(m, (float)dl[j][l], num);
            unsigned dxj = (unsigned)(px - mp.y);
            den += (dxj < 128u) ? m : 0.0f;
        }
        unsigned dxk = (unsigned)(px - (cpt & 1023));
        if (dxk < 128u)
            out[((size_t)kt << 14) + ((r - ((cpt >> 10) & 1023)) << 7) + (int)dxk] =
                num / fmaxf(den, EPSV);
    }
}

// -------------------------------------------------------------- launch ----
extern "C" void kernel_launch(void* const* d_in, const int* in_sizes, int n_in,
                              void* d_out, int out_size, void* d_ws, size_t ws_size,
                              hipStream_t stream) {
    const float* x     = (const float*)d_in[0];
    const float* sigma = (const float*)d_in[1];
    const float* c     = (const float*)d_in[2];
    const int*   cent  = (const int*)d_in[3];
    const float* M     = (const float*)d_in[4];
    const float* W1    = (const float*)d_in[5];
    const float* b1    = (const float*)d_in[6];
    const float* W2    = (const float*)d_in[7];
    const float* b2    = (const float*)d_in[8];
    const float* W3    = (const float*)d_in[9];
    const float* b3    = (const float*)d_in[10];
    float* out = (float*)d_out;

    float* ws       = (float*)d_ws;
    float* dist     = ws + WS_DIST;
    float* Msym     = ws + WS_MSYM;
    _Float16* W2f   = (_Float16*)(ws + WS_W2F);
    _Float16* D     = (_Float16*)(ws + WS_D);
    float* center   = ws + WS_CENTER;
    _Float16* G     = (_Float16*)(ws + WS_G);

    prep_kernel<<<256, 256, 0, stream>>>(M, W1, W2, c, b1, Msym, W2f, D);
    gfeat_kernel<<<576, 256, 0, stream>>>(x, sigma, W1, G);
    center2_kernel<<<256, 128, 0, stream>>>(G, D, W2, b2, W3, b3, cent, center);
    pix_kernel<<<2304, 256, 0, stream>>>(G, D, W2f, cent, b2, W3, b3, center, dist);
    merge_kernel<<<2304, 256, 0, stream>>>(dist, cent, Msym, out);
}

// Round 21
// 302.598 us; speedup vs baseline: 1.5034x; 1.0964x over previous
//
#include <hip/hip_runtime.h>
#include <hip/hip_bf16.h>

// InstanSeg v20 = v19 + wave-granular pix blocks.
// v19 post-mortem: 4-wave lockstep blocks hold residency until their
// slowest wave ends -> occ 17.4% vs 25% cap. Now pix = 9216 one-wave
// blocks (64 thr, launch_bounds(64) WITHOUT min-waves -> no v9 spill),
// each with its own exact ballot list (v11 precedent: same-wave LDS list,
// no barrier). + s_setprio(1) around MFMA (T5: helps independent 1-wave
// blocks; null only in lockstep). All else identical to passing v19.

#define HH    384
#define WW    384
#define NE    32
#define NK    256
#define HALF  64
#define HWSZ  (HH * WW)
#define EPSV  1e-6f
#define CAPX  192     // per-list candidate cap

typedef _Float16 half8 __attribute__((ext_vector_type(8)));
typedef _Float16 half2v __attribute__((ext_vector_type(2)));
typedef float floatx4 __attribute__((ext_vector_type(4)));

#define MFMA16(a, b, c) __builtin_amdgcn_mfma_f32_16x16x32_f16((a), (b), (c), 0, 0, 0)

__device__ __forceinline__ half2v pk_f16(float a, float b) {
    return __builtin_bit_cast(half2v, __builtin_amdgcn_cvt_pkrtz(a, b));
}

__device__ __forceinline__ int row_order(int ri) {
    return (ri & 1) ? (191 - (ri >> 1)) : (192 + (ri >> 1));
}

// ---- ws layout (float-element offsets) ----
#define WS_DIST   0            // 4,194,304 f32 (16 MB)
#define WS_MSYM   4194304      // 65,536 f32
#define WS_W2F    4259840      // 16,384 f16 = 8,192 f32
#define WS_D      4268032      // 32,768 f16 = 16,384 f32
#define WS_CENTER 4284416      // 256 f32
#define WS_G      5026560      // 18,874,368 f16 = 9,437,184 f32

// ---------------------------------------------------------------- prep ----
__global__ void prep_kernel(const float* __restrict__ M, const float* __restrict__ W1,
                            const float* __restrict__ W2, const float* __restrict__ c,
                            const float* __restrict__ b1,
                            float* __restrict__ Msym, _Float16* __restrict__ W2f,
                            _Float16* __restrict__ D) {
    int idx = blockIdx.x * 256 + threadIdx.x;
    {   // Msym
        int i = idx >> 8, j = idx & 255;
        Msym[idx] = (i == j) ? 1.0f : 0.5f * (M[i * NK + j] + M[j * NK + i]);
    }
    if (idx < 2048) {   // W2f B-frags: lane l elem j = W2[32s+8(l>>4)+j][16nt+(l&15)]
        int l = idx & 63;
        int col = ((idx >> 8) << 4) + (l & 15);
        int kb = ((idx >> 6) & 3) * 32 + 8 * (l >> 4);
        #pragma unroll
        for (int j = 0; j < 8; ++j)
            W2f[idx * 8 + j] = (_Float16)W2[(kb + j) * 128 + col];
    }
    if (idx < 32768) {  // D[k][h] = W1^T c_k - b1
        int k = idx >> 7, h = idx & 127;
        float s = -b1[h];
        #pragma unroll 8
        for (int e = 0; e < NE; ++e) s = fmaf(c[k * NE + e], W1[e * 128 + h], s);
        D[idx] = (_Float16)s;
    }
}

// --------------------------------------------------------------- gfeat ----
__global__ __launch_bounds__(256)
void gfeat_kernel(const float* __restrict__ x, const float* __restrict__ sigma,
                  const float* __restrict__ W1, _Float16* __restrict__ G) {
    int px = blockIdx.x * 256 + threadIdx.x;
    float f[34];
    #pragma unroll
    for (int e = 0; e < NE; ++e) f[e] = x[e * HWSZ + px];
    f[32] = sigma[px];
    f[33] = sigma[HWSZ + px];
    _Float16* gp = G + (size_t)px * 128;
    #pragma unroll 1
    for (int h0 = 0; h0 < 128; h0 += 8) {
        half8 hv;
        #pragma unroll
        for (int j = 0; j < 8; ++j) {
            float z = 0.0f;
            const float* w1 = W1 + (h0 + j);
            #pragma unroll
            for (int e = 0; e < 34; ++e) z = fmaf(f[e], w1[e * 128], z);
            hv[j] = (_Float16)z;
        }
        *(half8*)(gp + h0) = hv;
    }
}

// -------------------------------------------------------------- center2 ---
__global__ __launch_bounds__(128)
void center2_kernel(const _Float16* __restrict__ G, const _Float16* __restrict__ D,
                    const float* __restrict__ W2, const float* __restrict__ b2,
                    const float* __restrict__ W3, const float* __restrict__ b3,
                    const int* __restrict__ cent, float* __restrict__ center) {
    __shared__ float h1s[128];
    __shared__ float red[2];
    int k = blockIdx.x, j = threadIdx.x;
    int cy0 = cent[2 * k], cx0 = cent[2 * k + 1];
    const _Float16* g = G + ((size_t)cy0 * WW + cx0) * 128;
    h1s[j] = fmaxf((float)g[j] - (float)D[k * 128 + j], 0.0f);
    __syncthreads();
    float acc = 0.0f;
    #pragma unroll 8
    for (int i = 0; i < 128; ++i) acc = fmaf(h1s[i], W2[i * 128 + j], acc);
    float p = fmaxf(acc + b2[j], 0.0f) * W3[j];
    #pragma unroll
    for (int m = 1; m < 64; m <<= 1) p += __shfl_xor(p, m, 64);
    if ((j & 63) == 0) red[j >> 6] = p;
    __syncthreads();
    if (j == 0) center[k] = red[0] + red[1] + b3[0];
}

// ----------------------------------------------------------------- pix ----
// 9216 one-wave blocks (64 thr): block = (row, 16-px strip). Exact per-wave
// ballot list in LDS (same-wave write->read, v11 precedent). No barriers.
__global__ __launch_bounds__(64)
void pix_kernel(const _Float16* __restrict__ G, const _Float16* __restrict__ D,
                const _Float16* __restrict__ W2f, const int* __restrict__ cent,
                const float* __restrict__ b2, const float* __restrict__ W3,
                const float* __restrict__ b3, const float* __restrict__ center,
                float* __restrict__ dist) {
    __shared__ int   sjw[CAPX];
    __shared__ float sctr[CAPX];

    const int l   = threadIdx.x;
    const int lg  = l >> 4;
    const int xi  = l & 15;

    const int bid = blockIdx.x;
    const int r   = row_order(bid / 24);
    const int wx0 = (bid % 24) * 16;             // wave's 16-px x-origin

    // ---- exact candidate list for this 16-px span (ballot-prefix) ----
    int nc;
    {
        int base = 0;
        const int2* c2 = (const int2*)cent;
        #pragma unroll
        for (int cch = 0; cch < 4; ++cch) {
            int j = cch * 64 + l;
            int2 cc = c2[j];
            int ty = min(max(cc.x, HALF), HH - HALF) - HALF;
            int tx = min(max(cc.y, HALF), WW - HALF) - HALF;
            bool f = (r >= ty) && (r < ty + 128) &&
                     (tx <= wx0 + 15) && (tx + 127 >= wx0);
            unsigned long long m = __ballot(f);
            int pos = base + __popcll(m & ((1ull << l) - 1ull));
            if (f && pos < CAPX) {
                sjw[pos]  = (j << 20) | (ty << 10) | tx;
                sctr[pos] = center[j];
            }
            base += __popcll(m);
        }
        nc = min(base, CAPX);
    }

    // ---- loop-invariant registers (full W2 per wave) ----
    half8 B2w[8][4];
    const half8* W2f8 = (const half8*)W2f;
    #pragma unroll
    for (int n = 0; n < 8; ++n)
        #pragma unroll
        for (int s = 0; s < 4; ++s) B2w[n][s] = W2f8[(n * 4 + s) * 64 + l];

    float b2v[8][4];
    half2v w3pk[8][2];
    #pragma unroll
    for (int n = 0; n < 8; ++n) {
        #pragma unroll
        for (int q = 0; q < 4; ++q) b2v[n][q] = b2[16 * n + 4 * lg + q];
        #pragma unroll
        for (int q = 0; q < 2; ++q)
            w3pk[n][q] = half2v{(_Float16)W3[16 * n + 4 * lg + 2 * q],
                                (_Float16)W3[16 * n + 4 * lg + 2 * q + 1]};
    }
    const float b3s = b3[0];

    // G fragments for this wave's 16 px (loaded ONCE)
    half8 gA[4];
    {
        const char* Gb = (const char*)G + ((size_t)r * WW + wx0 + xi) * 256 + lg * 16;
        #pragma unroll
        for (int s = 0; s < 4; ++s) gA[s] = *(const half8*)(Gb + s * 64);
    }
    const half8 hz = half8{};

    // ---- candidate loop (D loaded inline; no prefetch registers) ----
    #pragma unroll 1
    for (int i = 0; i < nc; ++i) {
        int cp = sjw[i];
        int tx = cp & 1023, ty = (cp >> 10) & 1023, j = cp >> 20;

        const char* Dp = (const char*)D + j * 256 + lg * 16;
        half8 hin[4];
        #pragma unroll
        for (int s = 0; s < 4; ++s) {
            half8 dv = *(const half8*)(Dp + s * 64);
            hin[s] = __builtin_elementwise_max(gA[s] - dv, hz);
        }

        float p = 0.0f;
        __builtin_amdgcn_s_setprio(1);
        #pragma unroll
        for (int n = 0; n < 8; ++n) {
            floatx4 acc = floatx4{b2v[n][0], b2v[n][1], b2v[n][2], b2v[n][3]};
            #pragma unroll
            for (int s = 0; s < 4; ++s)
                acc = MFMA16(B2w[n][s], hin[s], acc);       // D[row=h2, col=px]
            half2v h0 = __builtin_elementwise_max(pk_f16(acc[0], acc[1]), half2v{});
            half2v h1 = __builtin_elementwise_max(pk_f16(acc[2], acc[3]), half2v{});
            p = __builtin_amdgcn_fdot2(h0, w3pk[n][0], p, false);
            p = __builtin_amdgcn_fdot2(h1, w3pk[n][1], p, false);
        }
        __builtin_amdgcn_s_setprio(0);
        p += __shfl_xor(p, 16, 64);
        p += __shfl_xor(p, 32, 64);

        if (lg == 0) {
            int xcol = wx0 + xi;
            unsigned dx = (unsigned)(xcol - tx);
            if (dx < 128u) {
                float d = p + b3s;
                float bc = sctr[i];
                float mm = fmaxf(fmaxf(d, bc), 0.0f);
                float lgv = mm + __logf(__expf(0.0f - mm) + __expf(d - mm) +
                                        __expf(bc - mm));
                dist[((size_t)j << 14) + ((r - ty) << 7) + (int)dx] = d + bc - lgv;
            }
        }
    }
}

// --------------------------------------------------------------- merge ----
// 2304 blocks of 256. dl staged as f16 (24KB) + per-t (m,tx) pairs in LDS.
__global__ __launch_bounds__(256)
void merge_kernel(const float* __restrict__ dist, const int* __restrict__ cent,
                  const float* __restrict__ Msym, float* __restrict__ out) {
    __shared__ _Float16 dl[CAPX][64];    // 24 KB
    __shared__ int   sjw[CAPX];
    __shared__ int2  mpk[4][CAPX];       // 6 KB {m bits, tx}
    __shared__ int   scnt;

    const int tid = threadIdx.x;
    const int l   = tid & 63;
    const int wv  = tid >> 6;
    const int r   = row_order(blockIdx.x / 6);
    const int xt  = blockIdx.x % 6;
    const int px  = xt * 64 + l;

    if (wv == 0) {
        int base = 0;
        const int2* c2 = (const int2*)cent;
        #pragma unroll
        for (int cch = 0; cch < 4; ++cch) {
            int j = cch * 64 + l;
            int2 cc = c2[j];
            int ty = min(max(cc.x, HALF), HH - HALF) - HALF;
            int tx = min(max(cc.y, HALF), WW - HALF) - HALF;
            bool f = (r >= ty) && (r < ty + 128) &&
                     (tx <= xt * 64 + 63) && (tx + 127 >= xt * 64);
            unsigned long long m = __ballot(f);
            int pos = base + __popcll(m & ((1ull << l) - 1ull));
            if (f && pos < CAPX) sjw[pos] = (j << 20) | (ty << 10) | tx;
            base += __popcll(m);
        }
        if (l == 0) scnt = min(base, CAPX);
    }
    __syncthreads();
    const int nc = scnt;

    #pragma unroll 1
    for (int j = wv; j < nc; j += 4) {
        int cp = sjw[j];
        int tx = cp & 1023, ty = (cp >> 10) & 1023, jj = cp >> 20;
        unsigned dx = (unsigned)(px - tx);
        float v = 0.0f;
        if (dx < 128u) v = dist[((size_t)jj << 14) + ((r - ty) << 7) + (int)dx];
        dl[j][l] = (_Float16)v;
    }
    __syncthreads();

    #pragma unroll 1
    for (int t = wv; t < nc; t += 4) {
        int cpt = sjw[t];
        int kt = cpt >> 20;
        const float* mrow = Msym + kt * NK;
        #pragma unroll
        for (int cch = 0; cch < 3; ++cch) {
            int j2 = cch * 64 + l;
            if (j2 < nc) {
                int cj = sjw[j2];
                mpk[wv][j2] = int2{__builtin_bit_cast(int, mrow[cj >> 20]),
                                   cj & 1023};
            }
        }
        float num = 0.0f, den = 0.0f;
        #pragma unroll 4
        for (int j = 0; j < nc; ++j) {
            int2 mp = mpk[wv][j];
            float m = __builtin_bit_cast(float, mp.x);
            num = fmaf(m, (float)dl[j][l], num);
            unsigned dxj = (unsigned)(px - mp.y);
            den += (dxj < 128u) ? m : 0.0f;
        }
        unsigned dxk = (unsigned)(px - (cpt & 1023));
        if (dxk < 128u)
            out[((size_t)kt << 14) + ((r - ((cpt >> 10) & 1023)) << 7) + (int)dxk] =
                num / fmaxf(den, EPSV);
    }
}

// -------------------------------------------------------------- launch ----
extern "C" void kernel_launch(void* const* d_in, const int* in_sizes, int n_in,
                              void* d_out, int out_size, void* d_ws, size_t ws_size,
                              hipStream_t stream) {
    const float* x     = (const float*)d_in[0];
    const float* sigma = (const float*)d_in[1];
    const float* c     = (const float*)d_in[2];
    const int*   cent  = (const int*)d_in[3];
    const float* M     = (const float*)d_in[4];
    const float* W1    = (const float*)d_in[5];
    const float* b1    = (const float*)d_in[6];
    const float* W2    = (const float*)d_in[7];
    const float* b2    = (const float*)d_in[8];
    const float* W3    = (const float*)d_in[9];
    const float* b3    = (const float*)d_in[10];
    float* out = (float*)d_out;

    float* ws       = (float*)d_ws;
    float* dist     = ws + WS_DIST;
    float* Msym     = ws + WS_MSYM;
    _Float16* W2f   = (_Float16*)(ws + WS_W2F);
    _Float16* D     = (_Float16*)(ws + WS_D);
    float* center   = ws + WS_CENTER;
    _Float16* G     = (_Float16*)(ws + WS_G);

    prep_kernel<<<256, 256, 0, stream>>>(M, W1, W2, c, b1, Msym, W2f, D);
    gfeat_kernel<<<576, 256, 0, stream>>>(x, sigma, W1, G);
    center2_kernel<<<256, 128, 0, stream>>>(G, D, W2, b2, W3, b3, cent, center);
    pix_kernel<<<9216, 64, 0, stream>>>(G, D, W2f, cent, b2, W3, b3, center, dist);
    merge_kernel<<<2304, 256, 0, stream>>>(dist, cent, Msym, out);
}